// Round 12
// baseline (251.314 us; speedup 1.0000x reference)
//
#include <hip/hip_runtime.h>
#include <hip/hip_bf16.h>

#define Bb 8
#define Nn 1024
#define Dd 256
#define Hh 4
#define ROWS 8192        // Bb*Nn
#define EPSf 1e-6f

typedef __bf16 bf16t;
typedef bf16t bf16x8 __attribute__((ext_vector_type(8)));
typedef float f32x4 __attribute__((ext_vector_type(4)));

#define MFMA(a, b, c) __builtin_amdgcn_mfma_f32_16x16x32_bf16((a), (b), (c), 0, 0, 0)
#define GLB_U32(p) ((const __attribute__((address_space(1))) unsigned int*)(p))
#define LDS_U32(p) ((__attribute__((address_space(3))) unsigned int*)(p))

__device__ __forceinline__ bf16x8 load8(const bf16t* p) { return *(const bf16x8*)p; }

// flexible input read: flag=1 -> buffer is bf16, flag=0 -> fp32
__device__ __forceinline__ float ldin(const void* p, size_t i, int flag) {
  return flag ? (float)((const bf16t*)p)[i] : ((const float*)p)[i];
}

// ---- ONE prep kernel: LN (blocks 0..2047) + transposes (2048..3327) +
//      params/flag (3328). Flag computed per-block from a 256-word x sample
//      (fp32 ~18/256 hits vs bf16 ~253/256 -- deterministic, >20 sigma). ----
__global__ __launch_bounds__(256) void k_prepall(
    const void* __restrict__ x,
    const void* __restrict__ wq, const void* __restrict__ wk,
    const void* __restrict__ wv, const void* __restrict__ wg,
    const void* __restrict__ ow,
    const void* __restrict__ lng, const void* __restrict__ lnb,
    const void* __restrict__ lnrg, const void* __restrict__ lnrb,
    const void* __restrict__ lnog, const void* __restrict__ lnob,
    const void* __restrict__ ob,
    bf16t* __restrict__ xn, bf16t* __restrict__ wtAll,
    bf16t* __restrict__ owT, float* __restrict__ pf, int* __restrict__ flagOut) {
  __shared__ int sflag;
  {
    if (threadIdx.x < 64) {
      int lane = threadIdx.x;
      int cnt = 0;
      const unsigned int* xw = (const unsigned int*)x;
#pragma unroll
      for (int i = 0; i < 4; ++i) {
        unsigned int b1 = (xw[lane * 4 + i] >> 8) & 0x7F;
        if (b1 >= 0x3B && b1 <= 0x43) cnt++;
      }
#pragma unroll
      for (int off = 32; off > 0; off >>= 1) cnt += __shfl_xor(cnt, off);
      if (lane == 0) sflag = (cnt > 128) ? 1 : 0;
    }
    __syncthreads();
  }
  const int flag = sflag;
  const int bid = blockIdx.x;

  if (bid < 2048) {
    // ---- LN: rows bid*4 .. bid*4+3, one wave per row ----
    int row = bid * 4 + (threadIdx.x >> 6);
    int lane = threadIdx.x & 63;
    size_t base = (size_t)row * Dd;
    float v[4]; float s = 0.f, s2 = 0.f;
#pragma unroll
    for (int i = 0; i < 4; ++i) {
      v[i] = ldin(x, base + lane * 4 + i, flag);
      s += v[i]; s2 += v[i] * v[i];
    }
#pragma unroll
    for (int off = 32; off > 0; off >>= 1) {
      s += __shfl_xor(s, off);
      s2 += __shfl_xor(s2, off);
    }
    float mu = s * (1.f / Dd);
    float var = fmaxf(s2 * (1.f / Dd) - mu * mu, 0.f);
    float rs = rsqrtf(var + EPSf);
#pragma unroll
    for (int i = 0; i < 4; ++i) {
      int d = lane * 4 + i;
      xn[base + d] = (bf16t)((v[i] - mu) * rs * ldin(lng, d, flag) + ldin(lnb, d, flag));
    }
  } else if (bid < 3328) {
    // ---- transposes: 1280 tiles of 32x32 (verbatim k_trall body) ----
    __shared__ bf16t tile[32][33];
    int t = bid - 2048;
    const void* in; bf16t* out; int R, C; size_t ibase;
    int r0, c0;
    if (t < 1024) {
      int w = t >> 8, z = (t >> 6) & 3, t64 = t & 63;
      r0 = (t64 >> 3) * 32; c0 = (t64 & 7) * 32;
      const void* srcs[4] = {wq, wk, wv, wg};
      const int tslot[4] = {0, 1, 3, 2};       // wq->t0, wk->t1, wv->t3, wg->t2
      in = srcs[w]; ibase = (size_t)z * 65536;
      out = wtAll + (size_t)(tslot[w] * 4 + z) * 65536;
      R = 256; C = 256;
    } else {
      int t2 = t - 1024;
      c0 = (t2 & 7) * 32; r0 = (t2 >> 3) * 32;
      in = ow; ibase = 0; out = owT; R = 1024; C = 256;
    }
    int tx = threadIdx.x & 31, ty = threadIdx.x >> 5;
#pragma unroll
    for (int i = 0; i < 32; i += 8)
      tile[ty + i][tx] = (bf16t)ldin(in, ibase + (size_t)(r0 + ty + i) * C + c0 + tx, flag);
    __syncthreads();
#pragma unroll
    for (int i = 0; i < 32; i += 8)
      out[(size_t)(c0 + ty + i) * R + r0 + tx] = tile[tx][ty + i];
  } else {
    // ---- params + flag publish ----
    const void* ps[7] = {lng, lnb, lnrg, lnrb, lnog, lnob, ob};
#pragma unroll
    for (int j = 0; j < 7; ++j)
      pf[j * 256 + threadIdx.x] = ldin(ps[j], threadIdx.x, flag);
    if (threadIdx.x == 0) *flagOut = flag;
  }
}

// ------- merged projection GEMM v2: C(8192 x 4096) = xn(8192x256) @ W^T -----
__global__ __launch_bounds__(256) void k_qkvg(
    const bf16t* __restrict__ xn, const bf16t* __restrict__ wtAll,
    bf16t* __restrict__ q, bf16t* __restrict__ kk,
    bf16t* __restrict__ g, bf16t* __restrict__ vt) {
  const int wave = threadIdx.x >> 6, lane = threadIdx.x & 63;
  const int quad = lane >> 4, l16 = lane & 15;
  const int mi = blockIdx.x, ni = blockIdx.y;
  const int row0 = mi * 128;
  const int instw = ni >> 1, colIn = (ni & 1) * 128;
  const int tt = instw >> 2, h = instw & 3;
  const int rB = (wave >> 1) * 64, cB = (wave & 1) * 64;

  const bf16t* Bsrc = wtAll + (size_t)instw * 65536 + (size_t)colIn * 256;

  __shared__ bf16t aT[4096];        // 8KB
  __shared__ bf16t bT[4096];        // 8KB
  __shared__ bf16t ct[128 * 136];   // 34KB epilogue tile (separate)

  f32x4 acc[4][4];
#pragma unroll
  for (int i = 0; i < 4; ++i)
#pragma unroll
    for (int j = 0; j < 4; ++j) acc[i][j] = (f32x4){0.f, 0.f, 0.f, 0.f};

  for (int k0 = 0; k0 < 256; k0 += 32) {
#pragma unroll
    for (int ii = 0; ii < 2; ++ii) {
      int inst = wave * 2 + ii;
      int idx = inst * 64 + lane;
      int r = idx >> 2, cp = idx & 3;
      int c = cp ^ ((r >> 1) & 3);
      __builtin_amdgcn_global_load_lds(GLB_U32(xn + (size_t)(row0 + r) * 256 + k0 + c * 8),
                                       LDS_U32(aT + inst * 512), 16, 0, 0);
    }
#pragma unroll
    for (int ii = 0; ii < 2; ++ii) {
      int inst = wave * 2 + ii;
      int idx = inst * 64 + lane;
      int r = idx >> 2, cp = idx & 3;
      int c = cp ^ ((r >> 1) & 3);
      __builtin_amdgcn_global_load_lds(GLB_U32(Bsrc + (size_t)r * 256 + k0 + c * 8),
                                       LDS_U32(bT + inst * 512), 16, 0, 0);
    }
    __syncthreads();

    bf16x8 aF[4], bF[4];
#pragma unroll
    for (int i = 0; i < 4; ++i) {
      int r = rB + i * 16 + l16;
      aF[i] = *(const bf16x8*)&aT[(r * 4 + (quad ^ ((r >> 1) & 3))) * 8];
    }
#pragma unroll
    for (int j = 0; j < 4; ++j) {
      int r = cB + j * 16 + l16;
      bF[j] = *(const bf16x8*)&bT[(r * 4 + (quad ^ ((r >> 1) & 3))) * 8];
    }
#pragma unroll
    for (int i = 0; i < 4; ++i)
#pragma unroll
      for (int j = 0; j < 4; ++j)
        acc[i][j] = MFMA(aF[i], bF[j], acc[i][j]);
    __syncthreads();
  }

  const bool tr = (tt == 3);
#pragma unroll
  for (int i = 0; i < 4; ++i)
#pragma unroll
    for (int j = 0; j < 4; ++j)
#pragma unroll
      for (int r = 0; r < 4; ++r) {
        int rl = rB + i * 16 + quad * 4 + r, cl = cB + j * 16 + l16;
        if (tr) ct[cl * 136 + rl] = (bf16t)acc[i][j][r];
        else    ct[rl * 136 + cl] = (bf16t)acc[i][j][r];
      }
  __syncthreads();
  if (!tr) {
    bf16t* base = (tt == 0 ? q : (tt == 1 ? kk : g)) +
                  (size_t)h * ROWS * Dd + (size_t)row0 * Dd + colIn;
#pragma unroll
    for (int it = 0; it < 8; ++it) {
      int rl = it * 16 + (threadIdx.x >> 4), c8 = (threadIdx.x & 15) * 8;
      *(bf16x8*)(base + (size_t)rl * Dd + c8) = *(const bf16x8*)&ct[rl * 136 + c8];
    }
  } else {
    int bb = row0 >> 10, n0 = row0 & 1023;
    bf16t* base = vt + (size_t)(h * Bb + bb) * Dd * Nn + (size_t)colIn * Nn + n0;
#pragma unroll
    for (int it = 0; it < 8; ++it) {
      int el = it * 16 + (threadIdx.x >> 4), c8 = (threadIdx.x & 15) * 8;
      *(bf16x8*)(base + (size_t)el * Nn + c8) = *(const bf16x8*)&ct[el * 136 + c8];
    }
  }
}

// -------- fused flash attention + gate + residual + LN_r -> tb[b,n,e,h] -----
// r11 structure (proven, frozen); xf replaced by direct x read via ldin.
__global__ __launch_bounds__(256) void k_flash(
    const bf16t* __restrict__ qb, const bf16t* __restrict__ kb,
    const bf16t* __restrict__ vtb, const bf16t* __restrict__ gb,
    const void* __restrict__ xin, const int* __restrict__ mask,
    const float* __restrict__ pf, const int* __restrict__ flagp,
    bf16t* __restrict__ tout) {
  const int flag = *flagp;
  const int wave = threadIdx.x >> 6, lane = threadIdx.x & 63;
  const int quad = lane >> 4, l16 = lane & 15;
  const int lin = blockIdx.x + 16 * blockIdx.y + 128 * blockIdx.z;
  const int hbp = lin & 31, tile = lin >> 5;   // (b,h) pairs spaced 32 -> same XCD
  const int b = hbp & 7, h = hbp >> 3;
  const int qrow0 = tile * 64 + wave * 16;

  const bf16t* Q = qb + (size_t)hbp * Nn * Dd;
  const bf16t* K = kb + (size_t)hbp * Nn * Dd;
  const bf16t* V = vtb + (size_t)hbp * Dd * Nn;   // (e, m)
  const bf16t* G = gb + (size_t)hbp * Nn * Dd;

  __shared__ bf16t klds[32 * 256];      // 16KB single-buffer
  __shared__ bf16t vlds[2][256 * 32];   // 2x16KB double-buffer
  __shared__ bf16t pl[4 * 16 * 32];     // 4KB per-wave P tiles
  __shared__ float cm[Nn];              // 4KB column mask          => 56KB

#define SWZ(row_) (((row_) & 3) ^ (((row_) >> 2) & 3))
#define STAGE_K(kt_) do {                                                      \
    _Pragma("unroll") for (int i_ = 0; i_ < 4; ++i_) {                         \
      int inst_ = wave * 4 + i_; int qq_ = inst_ * 64 + lane;                  \
      int r_ = qq_ >> 5, cp_ = qq_ & 31; int c_ = cp_ ^ (r_ & 15);             \
      __builtin_amdgcn_global_load_lds(                                        \
          GLB_U32(K + (size_t)((kt_) + r_) * Dd + c_ * 8),                     \
          LDS_U32(klds + inst_ * 512), 16, 0, 0); } } while (0)
#define STAGE_V(kt_, buf_) do {                                                \
    _Pragma("unroll") for (int i_ = 0; i_ < 4; ++i_) {                         \
      int inst_ = wave * 4 + i_; int qq_ = inst_ * 64 + lane;                  \
      int r_ = qq_ >> 2, cp_ = qq_ & 3; int c_ = cp_ ^ SWZ(r_);                \
      __builtin_amdgcn_global_load_lds(                                        \
          GLB_U32(V + (size_t)r_ * Nn + (kt_) + c_ * 8),                       \
          LDS_U32(vlds[buf_] + inst_ * 512), 16, 0, 0); } } while (0)

  STAGE_V(0, 0);
  STAGE_K(0);
  for (int i = threadIdx.x; i < Nn; i += 256) cm[i] = (float)mask[b * Nn + i];

  // Q fragments loaded once: A[m=l16][k=k8*32+quad*8+..]
  bf16x8 aq[8];
#pragma unroll
  for (int k8 = 0; k8 < 8; ++k8)
    aq[k8] = load8(Q + (size_t)(qrow0 + l16) * Dd + k8 * 32 + quad * 8);

  f32x4 oacc[16];
#pragma unroll
  for (int j = 0; j < 16; ++j) oacc[j] = (f32x4){0.f, 0.f, 0.f, 0.f};
  float lpart[4] = {0.f, 0.f, 0.f, 0.f};

  const float scale = 0.0625f;  // 1/sqrt(256)

  for (int kt = 0; kt < Nn; kt += 32) {
    const int vcur = (kt >> 5) & 1;
    __syncthreads();                 // TOP: drains K(kt)+V(kt) DMA
    if (kt + 32 < Nn) STAGE_V(kt + 32, vcur ^ 1);

    // ---- S = Q @ K_tile^T : 16x32
    f32x4 sacc[2];
    sacc[0] = (f32x4){0.f, 0.f, 0.f, 0.f};
    sacc[1] = (f32x4){0.f, 0.f, 0.f, 0.f};
#pragma unroll
    for (int k8 = 0; k8 < 8; ++k8)
#pragma unroll
      for (int j = 0; j < 2; ++j) {
        bf16x8 bk = *(const bf16x8*)&klds[((j * 16 + l16) * 32 + ((k8 * 4 + quad) ^ l16)) * 8];
        sacc[j] = MFMA(aq[k8], bk, sacc[j]);
      }

    // ---- P = mask ? exp(S*scale) : 0; deferred l
    float cmv0 = cm[kt + l16], cmv1 = cm[kt + 16 + l16];
#pragma unroll
    for (int j = 0; j < 2; ++j) {
      float cmv = j ? cmv1 : cmv0;
#pragma unroll
      for (int r = 0; r < 4; ++r) {
        float e = (cmv != 0.f) ? __expf(sacc[j][r] * scale) : 0.f;
        lpart[r] += e;
        int prow = quad * 4 + r;
        pl[wave * 512 + (prow * 4 + ((j * 2 + (l16 >> 3)) ^ SWZ(prow))) * 8 + (l16 & 7)] = (bf16t)e;
      }
    }

    __builtin_amdgcn_s_barrier();    // MID raw: K reads consumed; NO vmcnt drain
    if (kt + 32 < Nn) STAGE_K(kt + 32);

    // ---- PV: O(16x256) += P(16x32) @ V_tile(32x256)
    bf16x8 ap = *(const bf16x8*)&pl[wave * 512 + (l16 * 4 + (quad ^ SWZ(l16))) * 8];
#pragma unroll
    for (int j = 0; j < 16; ++j) {
      int e = j * 16 + l16;
      bf16x8 bv = *(const bf16x8*)&vlds[vcur][(e * 4 + (quad ^ SWZ(e))) * 8];
      oacc[j] = MFMA(ap, bv, oacc[j]);
    }
  }

  // ---- l: one cross-lane reduce at the end
#pragma unroll
  for (int r = 0; r < 4; ++r)
#pragma unroll
    for (int off = 1; off < 16; off <<= 1)
      lpart[r] += __shfl_xor(lpart[r], off);

  float inv[4];
#pragma unroll
  for (int r = 0; r < 4; ++r) {
    float rmv = cm[qrow0 + quad * 4 + r];
    inv[r] = (rmv != 0.f && lpart[r] > 1e-20f) ? 1.f / lpart[r] : 0.f;
  }
  float ps[4] = {0.f, 0.f, 0.f, 0.f}, pq[4] = {0.f, 0.f, 0.f, 0.f};
#pragma unroll
  for (int j = 0; j < 16; ++j) {
    int e = j * 16 + l16;
#pragma unroll
    for (int r = 0; r < 4; ++r) {
      int n = qrow0 + quad * 4 + r;
      float gv = (float)G[(size_t)n * Dd + e];
      float xv = ldin(xin, (size_t)(b * Nn + n) * Dd + e, flag);
      float o = oacc[j][r] * inv[r] * (1.f / (1.f + __expf(-gv))) + xv;
      oacc[j][r] = o;
      ps[r] += o; pq[r] += o * o;
    }
  }
#pragma unroll
  for (int r = 0; r < 4; ++r) {
#pragma unroll
    for (int off = 1; off < 16; off <<= 1) {
      ps[r] += __shfl_xor(ps[r], off);
      pq[r] += __shfl_xor(pq[r], off);
    }
    float mu = ps[r] * (1.f / Dd);
    float rs = rsqrtf(fmaxf(pq[r] * (1.f / Dd) - mu * mu, 0.f) + EPSf);
    ps[r] = mu; pq[r] = rs;
  }
#pragma unroll
  for (int j = 0; j < 16; ++j) {
    int e = j * 16 + l16;
    float lg = pf[2 * 256 + e], lb = pf[3 * 256 + e];
#pragma unroll
    for (int r = 0; r < 4; ++r) {
      int n = qrow0 + quad * 4 + r;
      tout[((size_t)(b * Nn + n) * Dd + e) * Hh + h] =
          (bf16t)((oacc[j][r] - ps[r]) * pq[r] * lg + lb);
    }
  }
#undef STAGE_K
#undef STAGE_V
#undef SWZ
}

// -------- y = t @ out_w + b + x, LN_o, *mask -> out (dtype per flag) --------
// now with DMA-staged A/B tiles (k_qkvg's proven stage/swizzle algebra)
__global__ __launch_bounds__(256) void k_out(
    const bf16t* __restrict__ t, const bf16t* __restrict__ owT,
    const void* __restrict__ xin, const int* __restrict__ mask,
    const float* __restrict__ pf, void* __restrict__ outp,
    const int* __restrict__ flagp) {
  const int flag = *flagp;
  const int wave = threadIdx.x >> 6, lane = threadIdx.x & 63;
  const int quad = lane >> 4, l16 = lane & 15;
  const int row0 = blockIdx.x * 16;

  __shared__ bf16t aT[512];     // 1KB: 16 rows x 32k
  __shared__ bf16t bT[8192];    // 16KB: 256 rows x 32k
  __shared__ float redS[4][16], redQ[4][16];

  f32x4 acc[4];
#pragma unroll
  for (int j = 0; j < 4; ++j) acc[j] = (f32x4){0.f, 0.f, 0.f, 0.f};

  for (int k0 = 0; k0 < 1024; k0 += 32) {
    if (wave == 0) {
      int r = lane >> 2, cp = lane & 3;
      int c = cp ^ ((r >> 1) & 3);
      __builtin_amdgcn_global_load_lds(GLB_U32(t + (size_t)(row0 + r) * 1024 + k0 + c * 8),
                                       LDS_U32(aT), 16, 0, 0);
    }
#pragma unroll
    for (int ii = 0; ii < 4; ++ii) {
      int inst = wave * 4 + ii;
      int idx = inst * 64 + lane;
      int r = idx >> 2, cp = idx & 3;
      int c = cp ^ ((r >> 1) & 3);
      __builtin_amdgcn_global_load_lds(GLB_U32(owT + (size_t)r * 1024 + k0 + c * 8),
                                       LDS_U32(bT + inst * 512), 16, 0, 0);
    }
    __syncthreads();
    bf16x8 a = *(const bf16x8*)&aT[(l16 * 4 + (quad ^ ((l16 >> 1) & 3))) * 8];
#pragma unroll
    for (int j = 0; j < 4; ++j) {
      int r = wave * 64 + j * 16 + l16;
      bf16x8 bb = *(const bf16x8*)&bT[(r * 4 + (quad ^ ((r >> 1) & 3))) * 8];
      acc[j] = MFMA(a, bb, acc[j]);
    }
    __syncthreads();
  }

  float ps[4] = {0.f, 0.f, 0.f, 0.f}, pq[4] = {0.f, 0.f, 0.f, 0.f};
#pragma unroll
  for (int j = 0; j < 4; ++j) {
    int e = wave * 64 + j * 16 + l16;
    float bias = pf[6 * 256 + e];
#pragma unroll
    for (int r = 0; r < 4; ++r) {
      int rr = row0 + quad * 4 + r;
      float o = acc[j][r] + bias + ldin(xin, (size_t)rr * Dd + e, flag);
      acc[j][r] = o;
      ps[r] += o; pq[r] += o * o;
    }
  }
#pragma unroll
  for (int r = 0; r < 4; ++r) {
#pragma unroll
    for (int off = 1; off < 16; off <<= 1) {
      ps[r] += __shfl_xor(ps[r], off);
      pq[r] += __shfl_xor(pq[r], off);
    }
    if (l16 == 0) { redS[wave][quad * 4 + r] = ps[r]; redQ[wave][quad * 4 + r] = pq[r]; }
  }
  __syncthreads();
  float mu[4], rs[4], mk[4];
#pragma unroll
  for (int r = 0; r < 4; ++r) {
    int rl = quad * 4 + r;
    float ts = redS[0][rl] + redS[1][rl] + redS[2][rl] + redS[3][rl];
    float tq = redQ[0][rl] + redQ[1][rl] + redQ[2][rl] + redQ[3][rl];
    float m_ = ts * (1.f / Dd);
    mu[r] = m_;
    rs[r] = rsqrtf(fmaxf(tq * (1.f / Dd) - m_ * m_, 0.f) + EPSf);
    mk[r] = (float)mask[row0 + rl];
  }
#pragma unroll
  for (int j = 0; j < 4; ++j) {
    int e = wave * 64 + j * 16 + l16;
    float lg = pf[4 * 256 + e], lb = pf[5 * 256 + e];
#pragma unroll
    for (int r = 0; r < 4; ++r) {
      int rr = row0 + quad * 4 + r;
      float o = ((acc[j][r] - mu[r]) * rs[r] * lg + lb) * mk[r];
      size_t idx = (size_t)rr * Dd + e;
      if (flag) ((bf16t*)outp)[idx] = (bf16t)o;
      else      ((float*)outp)[idx] = o;
    }
  }
}

extern "C" void kernel_launch(void* const* d_in, const int* in_sizes, int n_in,
                              void* d_out, int out_size, void* d_ws, size_t ws_size,
                              hipStream_t stream) {
  const void* x    = d_in[0];
  const int*  mask = (const int*)d_in[1];
  const void* wq   = d_in[2];
  const void* wk   = d_in[3];
  const void* wv   = d_in[4];
  const void* wg   = d_in[5];
  const void* ow   = d_in[6];
  const void* ob   = d_in[7];
  const void* lng  = d_in[8];
  const void* lnb  = d_in[9];
  const void* lnrg = d_in[10];
  const void* lnrb = d_in[11];
  const void* lnog = d_in[12];
  const void* lnob = d_in[13];

  // workspace layout (~86.5 MB)
  char* w = (char*)d_ws;
  int*   flag  = (int*)w;
  float* pf    = (float*)(w + 256);                              // 7*256 fp32 params
  w += 8192;
  bf16t* xn    = (bf16t*)w; w += (size_t)ROWS * Dd * 2;          // 4 MB
  bf16t* wtAll = (bf16t*)w; w += (size_t)16 * Dd * Dd * 2;       // 2 MB [t*4+h][e][d]
  bf16t* owT   = (bf16t*)w; w += (size_t)Dd * 1024 * 2;          // 0.5 MB
  bf16t* tb    = (bf16t*)w; w += (size_t)ROWS * 1024 * 2;        // 16 MB (b,n,e,h)
  bf16t* qb    = (bf16t*)w; w += (size_t)Hh * ROWS * Dd * 2;     // 16 MB (h,b,n,e)
  bf16t* kb    = (bf16t*)w; w += (size_t)Hh * ROWS * Dd * 2;     // 16 MB (h,b,n,e)
  bf16t* gb    = (bf16t*)w; w += (size_t)Hh * ROWS * Dd * 2;     // 16 MB (h,b,n,e)
  bf16t* vtb   = (bf16t*)w; w += (size_t)Hh * ROWS * Dd * 2;     // 16 MB (h,b,e,m)

  dim3 blk(256);
  k_prepall<<<dim3(3329), blk, 0, stream>>>(x, wq, wk, wv, wg, ow,
                                            lng, lnb, lnrg, lnrb, lnog, lnob, ob,
                                            xn, wtAll, owT, pf, flag);
  k_qkvg<<<dim3(64, 32), blk, 0, stream>>>(xn, wtAll, qb, kb, gb, vtb);
  k_flash<<<dim3(16, 8, 4), blk, 0, stream>>>(qb, kb, vtb, gb, x, mask, pf, flag, tb);
  k_out<<<dim3(512), blk, 0, stream>>>(tb, owT, x, mask, pf, d_out, flag);
}

// Round 13
// 210.365 us; speedup vs baseline: 1.1947x; 1.1947x over previous
//
#include <hip/hip_runtime.h>
#include <hip/hip_bf16.h>

#define Bb 8
#define Nn 1024
#define Dd 256
#define Hh 4
#define ROWS 8192        // Bb*Nn
#define EPSf 1e-6f

typedef __bf16 bf16t;
typedef bf16t bf16x8 __attribute__((ext_vector_type(8)));
typedef float f32x4 __attribute__((ext_vector_type(4)));

#define MFMA(a, b, c) __builtin_amdgcn_mfma_f32_16x16x32_bf16((a), (b), (c), 0, 0, 0)
#define GLB_U32(p) ((const __attribute__((address_space(1))) unsigned int*)(p))
#define LDS_U32(p) ((__attribute__((address_space(3))) unsigned int*)(p))

__device__ __forceinline__ bf16x8 load8(const bf16t* p) { return *(const bf16x8*)p; }

// flexible input read: flag=1 -> buffer is bf16, flag=0 -> fp32
__device__ __forceinline__ float ldin(const void* p, size_t i, int flag) {
  return flag ? (float)((const bf16t*)p)[i] : ((const float*)p)[i];
}

// ---- ONE prep kernel: LN+xf (blocks 0..2047) + transposes (2048..3327) +
//      params/flag (3328). Flag computed per-block from a 256-word x sample
//      (fp32 ~18/256 hits vs bf16 ~253/256 -- deterministic, >20 sigma). ----
__global__ __launch_bounds__(256) void k_prepall(
    const void* __restrict__ x,
    const void* __restrict__ wq, const void* __restrict__ wk,
    const void* __restrict__ wv, const void* __restrict__ wg,
    const void* __restrict__ ow,
    const void* __restrict__ lng, const void* __restrict__ lnb,
    const void* __restrict__ lnrg, const void* __restrict__ lnrb,
    const void* __restrict__ lnog, const void* __restrict__ lnob,
    const void* __restrict__ ob,
    bf16t* __restrict__ xn, float* __restrict__ xf, bf16t* __restrict__ wtAll,
    bf16t* __restrict__ owT, float* __restrict__ pf, int* __restrict__ flagOut) {
  __shared__ int sflag;
  {
    if (threadIdx.x < 64) {
      int lane = threadIdx.x;
      int cnt = 0;
      const unsigned int* xw = (const unsigned int*)x;
#pragma unroll
      for (int i = 0; i < 4; ++i) {
        unsigned int b1 = (xw[lane * 4 + i] >> 8) & 0x7F;
        if (b1 >= 0x3B && b1 <= 0x43) cnt++;
      }
#pragma unroll
      for (int off = 32; off > 0; off >>= 1) cnt += __shfl_xor(cnt, off);
      if (lane == 0) sflag = (cnt > 128) ? 1 : 0;
    }
    __syncthreads();
  }
  const int flag = sflag;
  const int bid = blockIdx.x;

  if (bid < 2048) {
    // ---- LN: rows bid*4 .. bid*4+3, one wave per row; also write xf ----
    int row = bid * 4 + (threadIdx.x >> 6);
    int lane = threadIdx.x & 63;
    size_t base = (size_t)row * Dd;
    float v[4]; float s = 0.f, s2 = 0.f;
#pragma unroll
    for (int i = 0; i < 4; ++i) {
      v[i] = ldin(x, base + lane * 4 + i, flag);
      s += v[i]; s2 += v[i] * v[i];
    }
#pragma unroll
    for (int off = 32; off > 0; off >>= 1) {
      s += __shfl_xor(s, off);
      s2 += __shfl_xor(s2, off);
    }
    float mu = s * (1.f / Dd);
    float var = fmaxf(s2 * (1.f / Dd) - mu * mu, 0.f);
    float rs = rsqrtf(var + EPSf);
#pragma unroll
    for (int i = 0; i < 4; ++i) {
      int d = lane * 4 + i;
      xf[base + d] = v[i];
      xn[base + d] = (bf16t)((v[i] - mu) * rs * ldin(lng, d, flag) + ldin(lnb, d, flag));
    }
  } else if (bid < 3328) {
    // ---- transposes: 1280 tiles of 32x32 ----
    __shared__ bf16t tile[32][33];
    int t = bid - 2048;
    const void* in; bf16t* out; int R, C; size_t ibase;
    int r0, c0;
    if (t < 1024) {
      int w = t >> 8, z = (t >> 6) & 3, t64 = t & 63;
      r0 = (t64 >> 3) * 32; c0 = (t64 & 7) * 32;
      const void* srcs[4] = {wq, wk, wv, wg};
      const int tslot[4] = {0, 1, 3, 2};       // wq->t0, wk->t1, wv->t3, wg->t2
      in = srcs[w]; ibase = (size_t)z * 65536;
      out = wtAll + (size_t)(tslot[w] * 4 + z) * 65536;
      R = 256; C = 256;
    } else {
      int t2 = t - 1024;
      c0 = (t2 & 7) * 32; r0 = (t2 >> 3) * 32;
      in = ow; ibase = 0; out = owT; R = 1024; C = 256;
    }
    int tx = threadIdx.x & 31, ty = threadIdx.x >> 5;
#pragma unroll
    for (int i = 0; i < 32; i += 8)
      tile[ty + i][tx] = (bf16t)ldin(in, ibase + (size_t)(r0 + ty + i) * C + c0 + tx, flag);
    __syncthreads();
#pragma unroll
    for (int i = 0; i < 32; i += 8)
      out[(size_t)(c0 + ty + i) * R + r0 + tx] = tile[tx][ty + i];
  } else {
    // ---- params + flag publish ----
    const void* ps[7] = {lng, lnb, lnrg, lnrb, lnog, lnob, ob};
#pragma unroll
    for (int j = 0; j < 7; ++j)
      pf[j * 256 + threadIdx.x] = ldin(ps[j], threadIdx.x, flag);
    if (threadIdx.x == 0) *flagOut = flag;
  }
}

// ------- merged projection GEMM v2: C(8192 x 4096) = xn(8192x256) @ W^T -----
__global__ __launch_bounds__(256) void k_qkvg(
    const bf16t* __restrict__ xn, const bf16t* __restrict__ wtAll,
    bf16t* __restrict__ q, bf16t* __restrict__ kk,
    bf16t* __restrict__ g, bf16t* __restrict__ vt) {
  const int wave = threadIdx.x >> 6, lane = threadIdx.x & 63;
  const int quad = lane >> 4, l16 = lane & 15;
  const int mi = blockIdx.x, ni = blockIdx.y;
  const int row0 = mi * 128;
  const int instw = ni >> 1, colIn = (ni & 1) * 128;
  const int tt = instw >> 2, h = instw & 3;
  const int rB = (wave >> 1) * 64, cB = (wave & 1) * 64;

  const bf16t* Bsrc = wtAll + (size_t)instw * 65536 + (size_t)colIn * 256;

  __shared__ bf16t aT[4096];        // 8KB
  __shared__ bf16t bT[4096];        // 8KB
  __shared__ bf16t ct[128 * 136];   // 34KB epilogue tile (separate)

  f32x4 acc[4][4];
#pragma unroll
  for (int i = 0; i < 4; ++i)
#pragma unroll
    for (int j = 0; j < 4; ++j) acc[i][j] = (f32x4){0.f, 0.f, 0.f, 0.f};

  for (int k0 = 0; k0 < 256; k0 += 32) {
#pragma unroll
    for (int ii = 0; ii < 2; ++ii) {
      int inst = wave * 2 + ii;
      int idx = inst * 64 + lane;
      int r = idx >> 2, cp = idx & 3;
      int c = cp ^ ((r >> 1) & 3);
      __builtin_amdgcn_global_load_lds(GLB_U32(xn + (size_t)(row0 + r) * 256 + k0 + c * 8),
                                       LDS_U32(aT + inst * 512), 16, 0, 0);
    }
#pragma unroll
    for (int ii = 0; ii < 2; ++ii) {
      int inst = wave * 2 + ii;
      int idx = inst * 64 + lane;
      int r = idx >> 2, cp = idx & 3;
      int c = cp ^ ((r >> 1) & 3);
      __builtin_amdgcn_global_load_lds(GLB_U32(Bsrc + (size_t)r * 256 + k0 + c * 8),
                                       LDS_U32(bT + inst * 512), 16, 0, 0);
    }
    __syncthreads();

    bf16x8 aF[4], bF[4];
#pragma unroll
    for (int i = 0; i < 4; ++i) {
      int r = rB + i * 16 + l16;
      aF[i] = *(const bf16x8*)&aT[(r * 4 + (quad ^ ((r >> 1) & 3))) * 8];
    }
#pragma unroll
    for (int j = 0; j < 4; ++j) {
      int r = cB + j * 16 + l16;
      bF[j] = *(const bf16x8*)&bT[(r * 4 + (quad ^ ((r >> 1) & 3))) * 8];
    }
#pragma unroll
    for (int i = 0; i < 4; ++i)
#pragma unroll
      for (int j = 0; j < 4; ++j)
        acc[i][j] = MFMA(aF[i], bF[j], acc[i][j]);
    __syncthreads();
  }

  const bool tr = (tt == 3);
#pragma unroll
  for (int i = 0; i < 4; ++i)
#pragma unroll
    for (int j = 0; j < 4; ++j)
#pragma unroll
      for (int r = 0; r < 4; ++r) {
        int rl = rB + i * 16 + quad * 4 + r, cl = cB + j * 16 + l16;
        if (tr) ct[cl * 136 + rl] = (bf16t)acc[i][j][r];
        else    ct[rl * 136 + cl] = (bf16t)acc[i][j][r];
      }
  __syncthreads();
  if (!tr) {
    bf16t* base = (tt == 0 ? q : (tt == 1 ? kk : g)) +
                  (size_t)h * ROWS * Dd + (size_t)row0 * Dd + colIn;
#pragma unroll
    for (int it = 0; it < 8; ++it) {
      int rl = it * 16 + (threadIdx.x >> 4), c8 = (threadIdx.x & 15) * 8;
      *(bf16x8*)(base + (size_t)rl * Dd + c8) = *(const bf16x8*)&ct[rl * 136 + c8];
    }
  } else {
    int bb = row0 >> 10, n0 = row0 & 1023;
    bf16t* base = vt + (size_t)(h * Bb + bb) * Dd * Nn + (size_t)colIn * Nn + n0;
#pragma unroll
    for (int it = 0; it < 8; ++it) {
      int el = it * 16 + (threadIdx.x >> 4), c8 = (threadIdx.x & 15) * 8;
      *(bf16x8*)(base + (size_t)el * Nn + c8) = *(const bf16x8*)&ct[el * 136 + c8];
    }
  }
}

// -------- fused flash attention + gate + residual + LN_r -> tb[b,n,e,h] -----
// r11 body verbatim (VGPR 128 / 70 us proven); epilogue reads fp32 xf.
__global__ __launch_bounds__(256) void k_flash(
    const bf16t* __restrict__ qb, const bf16t* __restrict__ kb,
    const bf16t* __restrict__ vtb, const bf16t* __restrict__ gb,
    const float* __restrict__ xf, const int* __restrict__ mask,
    const float* __restrict__ pf, bf16t* __restrict__ tout) {
  const int wave = threadIdx.x >> 6, lane = threadIdx.x & 63;
  const int quad = lane >> 4, l16 = lane & 15;
  const int lin = blockIdx.x + 16 * blockIdx.y + 128 * blockIdx.z;
  const int hbp = lin & 31, tile = lin >> 5;   // (b,h) pairs spaced 32 -> same XCD
  const int b = hbp & 7, h = hbp >> 3;
  const int qrow0 = tile * 64 + wave * 16;

  const bf16t* Q = qb + (size_t)hbp * Nn * Dd;
  const bf16t* K = kb + (size_t)hbp * Nn * Dd;
  const bf16t* V = vtb + (size_t)hbp * Dd * Nn;   // (e, m)
  const bf16t* G = gb + (size_t)hbp * Nn * Dd;

  __shared__ bf16t klds[32 * 256];      // 16KB single-buffer
  __shared__ bf16t vlds[2][256 * 32];   // 2x16KB double-buffer
  __shared__ bf16t pl[4 * 16 * 32];     // 4KB per-wave P tiles
  __shared__ float cm[Nn];              // 4KB column mask          => 56KB

#define SWZ(row_) (((row_) & 3) ^ (((row_) >> 2) & 3))
#define STAGE_K(kt_) do {                                                      \
    _Pragma("unroll") for (int i_ = 0; i_ < 4; ++i_) {                         \
      int inst_ = wave * 4 + i_; int qq_ = inst_ * 64 + lane;                  \
      int r_ = qq_ >> 5, cp_ = qq_ & 31; int c_ = cp_ ^ (r_ & 15);             \
      __builtin_amdgcn_global_load_lds(                                        \
          GLB_U32(K + (size_t)((kt_) + r_) * Dd + c_ * 8),                     \
          LDS_U32(klds + inst_ * 512), 16, 0, 0); } } while (0)
#define STAGE_V(kt_, buf_) do {                                                \
    _Pragma("unroll") for (int i_ = 0; i_ < 4; ++i_) {                         \
      int inst_ = wave * 4 + i_; int qq_ = inst_ * 64 + lane;                  \
      int r_ = qq_ >> 2, cp_ = qq_ & 3; int c_ = cp_ ^ SWZ(r_);                \
      __builtin_amdgcn_global_load_lds(                                        \
          GLB_U32(V + (size_t)r_ * Nn + (kt_) + c_ * 8),                       \
          LDS_U32(vlds[buf_] + inst_ * 512), 16, 0, 0); } } while (0)

  STAGE_V(0, 0);
  STAGE_K(0);
  for (int i = threadIdx.x; i < Nn; i += 256) cm[i] = (float)mask[b * Nn + i];

  // Q fragments loaded once: A[m=l16][k=k8*32+quad*8+..]
  bf16x8 aq[8];
#pragma unroll
  for (int k8 = 0; k8 < 8; ++k8)
    aq[k8] = load8(Q + (size_t)(qrow0 + l16) * Dd + k8 * 32 + quad * 8);

  f32x4 oacc[16];
#pragma unroll
  for (int j = 0; j < 16; ++j) oacc[j] = (f32x4){0.f, 0.f, 0.f, 0.f};
  float lpart[4] = {0.f, 0.f, 0.f, 0.f};

  const float scale = 0.0625f;  // 1/sqrt(256)

  for (int kt = 0; kt < Nn; kt += 32) {
    const int vcur = (kt >> 5) & 1;
    __syncthreads();                 // TOP: drains K(kt)+V(kt) DMA
    if (kt + 32 < Nn) STAGE_V(kt + 32, vcur ^ 1);

    // ---- S = Q @ K_tile^T : 16x32
    f32x4 sacc[2];
    sacc[0] = (f32x4){0.f, 0.f, 0.f, 0.f};
    sacc[1] = (f32x4){0.f, 0.f, 0.f, 0.f};
#pragma unroll
    for (int k8 = 0; k8 < 8; ++k8)
#pragma unroll
      for (int j = 0; j < 2; ++j) {
        bf16x8 bk = *(const bf16x8*)&klds[((j * 16 + l16) * 32 + ((k8 * 4 + quad) ^ l16)) * 8];
        sacc[j] = MFMA(aq[k8], bk, sacc[j]);
      }

    // ---- P = mask ? exp(S*scale) : 0; deferred l
    float cmv0 = cm[kt + l16], cmv1 = cm[kt + 16 + l16];
#pragma unroll
    for (int j = 0; j < 2; ++j) {
      float cmv = j ? cmv1 : cmv0;
#pragma unroll
      for (int r = 0; r < 4; ++r) {
        float e = (cmv != 0.f) ? __expf(sacc[j][r] * scale) : 0.f;
        lpart[r] += e;
        int prow = quad * 4 + r;
        pl[wave * 512 + (prow * 4 + ((j * 2 + (l16 >> 3)) ^ SWZ(prow))) * 8 + (l16 & 7)] = (bf16t)e;
      }
    }

    __builtin_amdgcn_s_barrier();    // MID raw: K reads consumed; NO vmcnt drain
    if (kt + 32 < Nn) STAGE_K(kt + 32);

    // ---- PV: O(16x256) += P(16x32) @ V_tile(32x256)
    bf16x8 ap = *(const bf16x8*)&pl[wave * 512 + (l16 * 4 + (quad ^ SWZ(l16))) * 8];
#pragma unroll
    for (int j = 0; j < 16; ++j) {
      int e = j * 16 + l16;
      bf16x8 bv = *(const bf16x8*)&vlds[vcur][(e * 4 + (quad ^ SWZ(e))) * 8];
      oacc[j] = MFMA(ap, bv, oacc[j]);
    }
  }

  // ---- l: one cross-lane reduce at the end
#pragma unroll
  for (int r = 0; r < 4; ++r)
#pragma unroll
    for (int off = 1; off < 16; off <<= 1)
      lpart[r] += __shfl_xor(lpart[r], off);

  float inv[4];
#pragma unroll
  for (int r = 0; r < 4; ++r) {
    float rmv = cm[qrow0 + quad * 4 + r];
    inv[r] = (rmv != 0.f && lpart[r] > 1e-20f) ? 1.f / lpart[r] : 0.f;
  }
  float ps[4] = {0.f, 0.f, 0.f, 0.f}, pq[4] = {0.f, 0.f, 0.f, 0.f};
#pragma unroll
  for (int j = 0; j < 16; ++j) {
    int e = j * 16 + l16;
#pragma unroll
    for (int r = 0; r < 4; ++r) {
      int n = qrow0 + quad * 4 + r;
      float gv = (float)G[(size_t)n * Dd + e];
      float xv = xf[(size_t)(b * Nn + n) * Dd + e];
      float o = oacc[j][r] * inv[r] * (1.f / (1.f + __expf(-gv))) + xv;
      oacc[j][r] = o;
      ps[r] += o; pq[r] += o * o;
    }
  }
#pragma unroll
  for (int r = 0; r < 4; ++r) {
#pragma unroll
    for (int off = 1; off < 16; off <<= 1) {
      ps[r] += __shfl_xor(ps[r], off);
      pq[r] += __shfl_xor(pq[r], off);
    }
    float mu = ps[r] * (1.f / Dd);
    float rs = rsqrtf(fmaxf(pq[r] * (1.f / Dd) - mu * mu, 0.f) + EPSf);
    ps[r] = mu; pq[r] = rs;
  }
#pragma unroll
  for (int j = 0; j < 16; ++j) {
    int e = j * 16 + l16;
    float lg = pf[2 * 256 + e], lb = pf[3 * 256 + e];
#pragma unroll
    for (int r = 0; r < 4; ++r) {
      int n = qrow0 + quad * 4 + r;
      tout[((size_t)(b * Nn + n) * Dd + e) * Hh + h] =
          (bf16t)((oacc[j][r] - ps[r]) * pq[r] * lg + lb);
    }
  }
#undef STAGE_K
#undef STAGE_V
#undef SWZ
}

// -------- y = t @ out_w + b + x, LN_o, *mask -> out (dtype per flag) --------
// DMA-staged A/B tiles; epilogue reads fp32 xf (no flag branch on loads).
__global__ __launch_bounds__(256) void k_out(
    const bf16t* __restrict__ t, const bf16t* __restrict__ owT,
    const float* __restrict__ xf, const int* __restrict__ mask,
    const float* __restrict__ pf, void* __restrict__ outp,
    const int* __restrict__ flagp) {
  const int flag = *flagp;
  const int wave = threadIdx.x >> 6, lane = threadIdx.x & 63;
  const int quad = lane >> 4, l16 = lane & 15;
  const int row0 = blockIdx.x * 16;

  __shared__ bf16t aT[512];     // 1KB: 16 rows x 32k
  __shared__ bf16t bT[8192];    // 16KB: 256 rows x 32k
  __shared__ float redS[4][16], redQ[4][16];

  f32x4 acc[4];
#pragma unroll
  for (int j = 0; j < 4; ++j) acc[j] = (f32x4){0.f, 0.f, 0.f, 0.f};

  for (int k0 = 0; k0 < 1024; k0 += 32) {
    if (wave == 0) {
      int r = lane >> 2, cp = lane & 3;
      int c = cp ^ ((r >> 1) & 3);
      __builtin_amdgcn_global_load_lds(GLB_U32(t + (size_t)(row0 + r) * 1024 + k0 + c * 8),
                                       LDS_U32(aT), 16, 0, 0);
    }
#pragma unroll
    for (int ii = 0; ii < 4; ++ii) {
      int inst = wave * 4 + ii;
      int idx = inst * 64 + lane;
      int r = idx >> 2, cp = idx & 3;
      int c = cp ^ ((r >> 1) & 3);
      __builtin_amdgcn_global_load_lds(GLB_U32(owT + (size_t)r * 1024 + k0 + c * 8),
                                       LDS_U32(bT + inst * 512), 16, 0, 0);
    }
    __syncthreads();
    bf16x8 a = *(const bf16x8*)&aT[(l16 * 4 + (quad ^ ((l16 >> 1) & 3))) * 8];
#pragma unroll
    for (int j = 0; j < 4; ++j) {
      int r = wave * 64 + j * 16 + l16;
      bf16x8 bb = *(const bf16x8*)&bT[(r * 4 + (quad ^ ((r >> 1) & 3))) * 8];
      acc[j] = MFMA(a, bb, acc[j]);
    }
    __syncthreads();
  }

  float ps[4] = {0.f, 0.f, 0.f, 0.f}, pq[4] = {0.f, 0.f, 0.f, 0.f};
#pragma unroll
  for (int j = 0; j < 4; ++j) {
    int e = wave * 64 + j * 16 + l16;
    float bias = pf[6 * 256 + e];
#pragma unroll
    for (int r = 0; r < 4; ++r) {
      int rr = row0 + quad * 4 + r;
      float o = acc[j][r] + bias + xf[(size_t)rr * Dd + e];
      acc[j][r] = o;
      ps[r] += o; pq[r] += o * o;
    }
  }
#pragma unroll
  for (int r = 0; r < 4; ++r) {
#pragma unroll
    for (int off = 1; off < 16; off <<= 1) {
      ps[r] += __shfl_xor(ps[r], off);
      pq[r] += __shfl_xor(pq[r], off);
    }
    if (l16 == 0) { redS[wave][quad * 4 + r] = ps[r]; redQ[wave][quad * 4 + r] = pq[r]; }
  }
  __syncthreads();
  float mu[4], rs[4], mk[4];
#pragma unroll
  for (int r = 0; r < 4; ++r) {
    int rl = quad * 4 + r;
    float ts = redS[0][rl] + redS[1][rl] + redS[2][rl] + redS[3][rl];
    float tq = redQ[0][rl] + redQ[1][rl] + redQ[2][rl] + redQ[3][rl];
    float m_ = ts * (1.f / Dd);
    mu[r] = m_;
    rs[r] = rsqrtf(fmaxf(tq * (1.f / Dd) - m_ * m_, 0.f) + EPSf);
    mk[r] = (float)mask[row0 + rl];
  }
#pragma unroll
  for (int j = 0; j < 4; ++j) {
    int e = wave * 64 + j * 16 + l16;
    float lg = pf[4 * 256 + e], lb = pf[5 * 256 + e];
#pragma unroll
    for (int r = 0; r < 4; ++r) {
      int rr = row0 + quad * 4 + r;
      float o = ((acc[j][r] - mu[r]) * rs[r] * lg + lb) * mk[r];
      size_t idx = (size_t)rr * Dd + e;
      if (flag) ((bf16t*)outp)[idx] = (bf16t)o;
      else      ((float*)outp)[idx] = o;
    }
  }
}

extern "C" void kernel_launch(void* const* d_in, const int* in_sizes, int n_in,
                              void* d_out, int out_size, void* d_ws, size_t ws_size,
                              hipStream_t stream) {
  const void* x    = d_in[0];
  const int*  mask = (const int*)d_in[1];
  const void* wq   = d_in[2];
  const void* wk   = d_in[3];
  const void* wv   = d_in[4];
  const void* wg   = d_in[5];
  const void* ow   = d_in[6];
  const void* ob   = d_in[7];
  const void* lng  = d_in[8];
  const void* lnb  = d_in[9];
  const void* lnrg = d_in[10];
  const void* lnrb = d_in[11];
  const void* lnog = d_in[12];
  const void* lnob = d_in[13];

  // workspace layout (~94.5 MB)
  char* w = (char*)d_ws;
  int*   flag  = (int*)w;
  float* pf    = (float*)(w + 256);                              // 7*256 fp32 params
  w += 8192;
  float* xf    = (float*)w; w += (size_t)ROWS * Dd * 4;          // 8 MB fp32 x
  bf16t* xn    = (bf16t*)w; w += (size_t)ROWS * Dd * 2;          // 4 MB
  bf16t* wtAll = (bf16t*)w; w += (size_t)16 * Dd * Dd * 2;       // 2 MB [t*4+h][e][d]
  bf16t* owT   = (bf16t*)w; w += (size_t)Dd * 1024 * 2;          // 0.5 MB
  bf16t* tb    = (bf16t*)w; w += (size_t)ROWS * 1024 * 2;        // 16 MB (b,n,e,h)
  bf16t* qb    = (bf16t*)w; w += (size_t)Hh * ROWS * Dd * 2;     // 16 MB (h,b,n,e)
  bf16t* kb    = (bf16t*)w; w += (size_t)Hh * ROWS * Dd * 2;     // 16 MB (h,b,n,e)
  bf16t* gb    = (bf16t*)w; w += (size_t)Hh * ROWS * Dd * 2;     // 16 MB (h,b,n,e)
  bf16t* vtb   = (bf16t*)w; w += (size_t)Hh * ROWS * Dd * 2;     // 16 MB (h,b,e,m)

  dim3 blk(256);
  k_prepall<<<dim3(3329), blk, 0, stream>>>(x, wq, wk, wv, wg, ow,
                                            lng, lnb, lnrg, lnrb, lnog, lnob, ob,
                                            xn, xf, wtAll, owT, pf, flag);
  k_qkvg<<<dim3(64, 32), blk, 0, stream>>>(xn, wtAll, qb, kb, gb, vtb);
  k_flash<<<dim3(16, 8, 4), blk, 0, stream>>>(qb, kb, vtb, gb, xf, mask, pf, tb);
  k_out<<<dim3(512), blk, 0, stream>>>(tb, owT, xf, mask, pf, d_out, flag);
}